// Round 1
// 884.127 us; speedup vs baseline: 1.7120x; 1.7120x over previous
//
#include <hip/hip_runtime.h>
#include <math.h>

#define B_   16
#define CIN  64
#define COUT 64
#define H_   256
#define W_   256

typedef short s16x8  __attribute__((ext_vector_type(8)));
typedef float f32x16 __attribute__((ext_vector_type(16)));

// Split fp32 into two bf16 (truncation): v = hi + lo + O(2^-16 * v)
__device__ __forceinline__ void split_bf16(float v, unsigned short& hi, unsigned short& lo) {
    unsigned u = __float_as_uint(v);
    hi = (unsigned short)(u >> 16);
    float hif = __uint_as_float(u & 0xffff0000u);
    lo = (unsigned short)(__float_as_uint(v - hif) >> 16);
}

// ---------------------------------------------------------------------------
// 1) pooled[b*64+c] = mean over H*W of inputs[b][c][:][:]
__global__ __launch_bounds__(256) void pool_kernel(const float* __restrict__ x,
                                                   float* __restrict__ pooled) {
    const int plane = blockIdx.x;  // 0..1023 = b*64+c
    const float4* p = (const float4*)(x + (size_t)plane * (H_ * W_));
    float s = 0.f;
    for (int i = threadIdx.x; i < (H_ * W_) / 4; i += 256) {
        float4 v = p[i];
        s += (v.x + v.y) + (v.z + v.w);
    }
    #pragma unroll
    for (int off = 32; off > 0; off >>= 1) s += __shfl_down(s, off);
    __shared__ float red[4];
    if ((threadIdx.x & 63) == 0) red[threadIdx.x >> 6] = s;
    __syncthreads();
    if (threadIdx.x == 0)
        pooled[plane] = (red[0] + red[1] + red[2] + red[3]) * (1.f / (H_ * W_));
}

// ---------------------------------------------------------------------------
// 2) routing[b*4+e] = sigmoid(dot(pooled[b], fc_w[e]) + fc_b[e])
__global__ void routing_kernel(const float* __restrict__ pooled,
                               const float* __restrict__ fc_w,
                               const float* __restrict__ fc_b,
                               float* __restrict__ routing) {
    const int tid = threadIdx.x;          // 64 threads
    const int b = tid >> 2, e = tid & 3;
    float s = fc_b[e];
    for (int c = 0; c < CIN; ++c) s += pooled[b * CIN + c] * fc_w[e * CIN + c];
    routing[b * 4 + e] = 1.f / (1.f + expf(-s));
}

// ---------------------------------------------------------------------------
// 3) mixed weights, pre-split into bf16 hi/lo, laid out per (b, ic-chunk q):
//    chunk (18432 shorts = 36864 B, linear-copyable to LDS):
//      [half(2)][tap(9)][oc(64)][icL(16)]
// thread gid -> (b, q, oc, icL); computes all 9 taps.
__global__ __launch_bounds__(256) void mix_kernel(const float* __restrict__ routing,
                                                  const float* __restrict__ weight,
                                                  unsigned short* __restrict__ mixed) {
    const int gid = blockIdx.x * 256 + threadIdx.x;   // 0..65535
    const int icL = gid & 15;
    const int oc  = (gid >> 4) & 63;
    const int q   = (gid >> 10) & 3;
    const int b   = gid >> 12;
    const int ic  = q * 16 + icL;

    float r[4];
    #pragma unroll
    for (int e = 0; e < 4; ++e) r[e] = routing[b * 4 + e];

    float s[9];
    #pragma unroll
    for (int t = 0; t < 9; ++t) s[t] = 0.f;
    #pragma unroll
    for (int e = 0; e < 4; ++e) {
        const float* wp = weight + (((size_t)e * COUT + oc) * CIN + ic) * 9;
        #pragma unroll
        for (int t = 0; t < 9; ++t) s[t] = fmaf(r[e], wp[t], s[t]);
    }
    unsigned short* dst = mixed + (size_t)(b * 4 + q) * 18432 + oc * 16 + icL;
    #pragma unroll
    for (int t = 0; t < 9; ++t) {
        unsigned short hi, lo;
        split_bf16(s[t], hi, lo);
        dst[t * 1024]        = hi;   // half 0
        dst[9216 + t * 1024] = lo;   // half 1
    }
}

// ---------------------------------------------------------------------------
// 4) conv as tap-decomposed implicit GEMM on MFMA (split-bf16, 3 passes).
// Block tile: all 64 oc x (8 rows x 32 cols). 4 waves; each wave: M=64 (2 mb),
// N=64 (2 rows, one 32-col N-block each), mfma_f32_32x32x16_bf16.
// K loop: 4 ic-chunks of 16 x 9 taps (K=16 per MFMA step).
// A/B frags use the SAME assumed per-lane k-map ((lane>>5)*8+i) -> any
// consistent permutation is correct (dot product is k-order invariant).
__global__ __launch_bounds__(256, 2) void conv_kernel(const float* __restrict__ x,
                                                      const unsigned short* __restrict__ wmix,
                                                      float* __restrict__ y) {
    __shared__ __align__(16) unsigned short in_hi[10 * 34 * 16];   // 10880 B
    __shared__ __align__(16) unsigned short in_lo[10 * 34 * 16];   // 10880 B
    __shared__ __align__(16) unsigned short wt_s[2 * 9 * 64 * 16]; // 36864 B

    const int tid  = threadIdx.x;
    const int lane = tid & 63;
    const int wv   = tid >> 6;        // wave 0..3 -> output rows {2wv, 2wv+1}
    const int n    = lane & 31;       // MFMA col (output w within tile / oc row for A)
    const int kseg = lane >> 5;       // k-half select

    const int w0 = blockIdx.x * 32;
    const int h0 = blockIdx.y * 8;
    const int b  = blockIdx.z;

    // staging positions: 340 = 10*34 (r,c) halo positions; thread covers p0 (+p1)
    const int p0 = tid;
    const int r0 = p0 / 34, c0 = p0 - r0 * 34;
    const int p1 = tid + 256;
    const int r1 = p1 / 34, c1 = p1 - r1 * 34;
    const bool has1 = (p1 < 340);

    const int gh0 = h0 - 1 + r0, gw0 = w0 - 1 + c0;
    const int gh1 = h0 - 1 + r1, gw1 = w0 - 1 + c1;
    const bool ok0 = ((unsigned)gh0 < H_) && ((unsigned)gw0 < W_);
    const bool ok1 = has1 && ((unsigned)gh1 < H_) && ((unsigned)gw1 < W_);

    const float* xb = x + (size_t)b * CIN * H_ * W_;
    const float* g0 = xb + (ok0 ? (gh0 * W_ + gw0) : 0);
    const float* g1 = xb + (ok1 ? (gh1 * W_ + gw1) : 0);
    const int l0 = (r0 * 34 + c0) * 16;
    const int l1 = (r1 * 34 + c1) * 16;
    const int rot = (tid >> 2) << 1;  // ic write rotation -> ~2-way LDS banks

    f32x16 acc[2][2];
    #pragma unroll
    for (int mb = 0; mb < 2; ++mb)
        #pragma unroll
        for (int nb = 0; nb < 2; ++nb)
            #pragma unroll
            for (int j = 0; j < 16; ++j) acc[mb][nb][j] = 0.f;

    const int abase = n * 16 + kseg * 8;                   // + tap*1024 + mb*512 (+9216 for lo)
    const int bbase = ((wv * 2) * 34 + n) * 16 + kseg * 8; // + (nb+kh)*544 + kw*16

    #pragma unroll 1
    for (int q = 0; q < 4; ++q) {
        __syncthreads();
        // ---- stage weights: linear 36864 B copy (layout matches LDS exactly)
        {
            const uint4* src = (const uint4*)wmix + (size_t)(b * 4 + q) * 2304;
            uint4* dst = (uint4*)wt_s;
            #pragma unroll
            for (int i = 0; i < 9; ++i) dst[i * 256 + tid] = src[i * 256 + tid];
        }
        // ---- stage input chunk (16 ics), convert fp32 -> bf16 hi/lo
        {
            const float* s0 = g0 + (size_t)q * 16 * (H_ * W_);
            #pragma unroll
            for (int i = 0; i < 16; ++i) {
                const int ic = (i + rot) & 15;
                float vv = ok0 ? s0[(size_t)ic * (H_ * W_)] : 0.f;
                unsigned short hi, lo; split_bf16(vv, hi, lo);
                in_hi[l0 + ic] = hi; in_lo[l0 + ic] = lo;
            }
            if (has1) {
                const float* s1 = g1 + (size_t)q * 16 * (H_ * W_);
                #pragma unroll
                for (int i = 0; i < 16; ++i) {
                    const int ic = (i + rot) & 15;
                    float vv = ok1 ? s1[(size_t)ic * (H_ * W_)] : 0.f;
                    unsigned short hi, lo; split_bf16(vv, hi, lo);
                    in_hi[l1 + ic] = hi; in_lo[l1 + ic] = lo;
                }
            }
        }
        __syncthreads();

        // ---- 9 taps x (2 mb x 2 nb x 3 passes) MFMAs
        #pragma unroll
        for (int kh = 0; kh < 3; ++kh) {
            #pragma unroll
            for (int kw = 0; kw < 3; ++kw) {
                const int tap = kh * 3 + kw;
                s16x8 ahi[2], alo[2];
                #pragma unroll
                for (int mb = 0; mb < 2; ++mb) {
                    const int aoff = tap * 1024 + mb * 512 + abase;
                    ahi[mb] = *(const s16x8*)&wt_s[aoff];
                    alo[mb] = *(const s16x8*)&wt_s[9216 + aoff];
                }
                #pragma unroll
                for (int nb = 0; nb < 2; ++nb) {
                    const int boff = bbase + (nb + kh) * 544 + kw * 16;
                    const s16x8 bhi = *(const s16x8*)&in_hi[boff];
                    const s16x8 blo = *(const s16x8*)&in_lo[boff];
                    #pragma unroll
                    for (int mb = 0; mb < 2; ++mb) {
                        acc[mb][nb] = __builtin_amdgcn_mfma_f32_32x32x16_bf16(ahi[mb], bhi, acc[mb][nb], 0, 0, 0);
                        acc[mb][nb] = __builtin_amdgcn_mfma_f32_32x32x16_bf16(alo[mb], bhi, acc[mb][nb], 0, 0, 0);
                        acc[mb][nb] = __builtin_amdgcn_mfma_f32_32x32x16_bf16(ahi[mb], blo, acc[mb][nb], 0, 0, 0);
                    }
                }
            }
        }
    }

    // ---- epilogue: C/D layout (verified): col = lane&31, row = (r&3)+8*(r>>2)+4*kseg
    #pragma unroll
    for (int mb = 0; mb < 2; ++mb) {
        #pragma unroll
        for (int nb = 0; nb < 2; ++nb) {
            const int hrow = h0 + wv * 2 + nb;
            #pragma unroll
            for (int r = 0; r < 16; ++r) {
                const int oc = mb * 32 + (r & 3) + 8 * (r >> 2) + 4 * kseg;
                y[(((size_t)b * COUT + oc) * H_ + hrow) * W_ + w0 + n] = acc[mb][nb][r];
            }
        }
    }
}

// ---------------------------------------------------------------------------
extern "C" void kernel_launch(void* const* d_in, const int* in_sizes, int n_in,
                              void* d_out, int out_size, void* d_ws, size_t ws_size,
                              hipStream_t stream) {
    const float* x      = (const float*)d_in[0];  // [16,64,256,256]
    const float* weight = (const float*)d_in[1];  // [4,64,64,3,3]
    const float* fc_w   = (const float*)d_in[2];  // [4,64]
    const float* fc_b   = (const float*)d_in[3];  // [4]
    float* out = (float*)d_out;

    float* ws      = (float*)d_ws;
    float* pooled  = ws;                                   // 1024 floats
    float* routing = ws + 1024;                            // 64 floats
    unsigned short* mixed = (unsigned short*)(ws + 1088);  // 1179648 shorts (~2.36 MB)

    pool_kernel<<<B_ * CIN, 256, 0, stream>>>(x, pooled);
    routing_kernel<<<1, 64, 0, stream>>>(pooled, fc_w, fc_b, routing);
    mix_kernel<<<(B_ * 4 * COUT * 16) / 256, 256, 0, stream>>>(routing, weight, mixed);

    dim3 grid(W_ / 32, H_ / 8, B_);
    conv_kernel<<<grid, 256, 0, stream>>>(x, mixed, out);
}

// Round 2
// 644.949 us; speedup vs baseline: 2.3469x; 1.3708x over previous
//
#include <hip/hip_runtime.h>
#include <math.h>

#define B_   16
#define CIN  64
#define COUT 64
#define H_   256
#define W_   256

typedef short s16x8  __attribute__((ext_vector_type(8)));
typedef float f32x16 __attribute__((ext_vector_type(16)));

// Split fp32 into two bf16 (truncation): v = hi + lo + O(2^-16 * v)
__device__ __forceinline__ void split_bf16(float v, unsigned short& hi, unsigned short& lo) {
    unsigned u = __float_as_uint(v);
    hi = (unsigned short)(u >> 16);
    float hif = __uint_as_float(u & 0xffff0000u);
    lo = (unsigned short)(__float_as_uint(v - hif) >> 16);
}

// ---------------------------------------------------------------------------
// 1) pooled[b*64+c] = mean over H*W of inputs[b][c][:][:]
__global__ __launch_bounds__(256) void pool_kernel(const float* __restrict__ x,
                                                   float* __restrict__ pooled) {
    const int plane = blockIdx.x;  // 0..1023 = b*64+c
    const float4* p = (const float4*)(x + (size_t)plane * (H_ * W_));
    float s = 0.f;
    for (int i = threadIdx.x; i < (H_ * W_) / 4; i += 256) {
        float4 v = p[i];
        s += (v.x + v.y) + (v.z + v.w);
    }
    #pragma unroll
    for (int off = 32; off > 0; off >>= 1) s += __shfl_down(s, off);
    __shared__ float red[4];
    if ((threadIdx.x & 63) == 0) red[threadIdx.x >> 6] = s;
    __syncthreads();
    if (threadIdx.x == 0)
        pooled[plane] = (red[0] + red[1] + red[2] + red[3]) * (1.f / (H_ * W_));
}

// ---------------------------------------------------------------------------
// 2) routing[b*4+e] = sigmoid(dot(pooled[b], fc_w[e]) + fc_b[e])
__global__ void routing_kernel(const float* __restrict__ pooled,
                               const float* __restrict__ fc_w,
                               const float* __restrict__ fc_b,
                               float* __restrict__ routing) {
    const int tid = threadIdx.x;          // 64 threads
    const int b = tid >> 2, e = tid & 3;
    float s = fc_b[e];
    for (int c = 0; c < CIN; ++c) s += pooled[b * CIN + c] * fc_w[e * CIN + c];
    routing[b * 4 + e] = 1.f / (1.f + expf(-s));
}

// ---------------------------------------------------------------------------
// 3) mixed weights in exact MFMA A-fragment order, bf16 hi/lo.
// Per (b, q-chunk): 36 fragments of 512 shorts:
//   frag f = tap*4 + half*2 + mb  (tap 0..8, half 0=hi 1=lo, mb 0..1)
//   frag layout: [lane(64)][8]: lane l -> oc = mb*32 + (l&31),
//                               ic = q*16 + (l>>5)*8 + j
// So conv waves load A fragments global->VGPR fully coalesced (16B/lane).
__global__ __launch_bounds__(256) void mix_kernel(const float* __restrict__ routing,
                                                  const float* __restrict__ weight,
                                                  unsigned short* __restrict__ mixed) {
    const int gid = blockIdx.x * 256 + threadIdx.x;   // 0..65535
    const int icL = gid & 15;
    const int oc  = (gid >> 4) & 63;
    const int q   = (gid >> 10) & 3;
    const int b   = gid >> 12;
    const int ic  = q * 16 + icL;

    float r[4];
    #pragma unroll
    for (int e = 0; e < 4; ++e) r[e] = routing[b * 4 + e];

    float s[9];
    #pragma unroll
    for (int t = 0; t < 9; ++t) s[t] = 0.f;
    #pragma unroll
    for (int e = 0; e < 4; ++e) {
        const float* wp = weight + (((size_t)e * COUT + oc) * CIN + ic) * 9;
        #pragma unroll
        for (int t = 0; t < 9; ++t) s[t] = fmaf(r[e], wp[t], s[t]);
    }
    unsigned short* base = mixed + (size_t)(b * 4 + q) * 18432;
    const int mb = oc >> 5;
    const int l  = (oc & 31) + ((icL >> 3) << 5);
    const int j  = icL & 7;
    #pragma unroll
    for (int t = 0; t < 9; ++t) {
        unsigned short hi, lo;
        split_bf16(s[t], hi, lo);
        base[(t * 4 + 0 + mb) * 512 + l * 8 + j] = hi;   // half 0
        base[(t * 4 + 2 + mb) * 512 + l * 8 + j] = lo;   // half 1
    }
}

// ---------------------------------------------------------------------------
// 4) conv: tap-decomposed implicit GEMM, split-bf16 3-pass.
// A (weights) from global (L2-resident, fragment order) -> VGPR, ping-pong
// prefetched across taps. B (input) through LDS, hi/lo packed b128 writes,
// 16B-chunk XOR swizzle (c ^= (c>>3)&7) on BOTH write and read.
// Block: 64oc x 8rows x 32cols, 4 waves (wave wv: rows 2wv, 2wv+1).
__global__ __launch_bounds__(256, 3) void conv_kernel(const float* __restrict__ x,
                                                      const unsigned short* __restrict__ wmix,
                                                      float* __restrict__ y) {
    __shared__ __align__(16) unsigned short in_hi[10 * 34 * 16];   // 10880 B
    __shared__ __align__(16) unsigned short in_lo[10 * 34 * 16];   // 10880 B

    const int tid  = threadIdx.x;
    const int lane = tid & 63;
    const int wv   = tid >> 6;
    const int n    = lane & 31;       // MFMA col / output w-in-tile
    const int kseg = lane >> 5;       // k-half select

    const int w0 = blockIdx.x * 32;
    const int h0 = blockIdx.y * 8;
    const int b  = blockIdx.z;

    // staging: 340 halo positions; thread covers p0 (+p1 if tid<84)
    const int p0 = tid;
    const int r0 = p0 / 34, c0 = p0 - r0 * 34;
    const int p1 = tid + 256;
    const int r1 = p1 / 34, c1 = p1 - r1 * 34;
    const bool has1 = (p1 < 340);

    const int gh0 = h0 - 1 + r0, gw0 = w0 - 1 + c0;
    const int gh1 = h0 - 1 + r1, gw1 = w0 - 1 + c1;
    const bool ok0 = ((unsigned)gh0 < H_) && ((unsigned)gw0 < W_);
    const bool ok1 = has1 && ((unsigned)gh1 < H_) && ((unsigned)gw1 < W_);

    const float* xb = x + (size_t)b * CIN * H_ * W_;
    const float* g0 = xb + (ok0 ? (gh0 * W_ + gw0) : 0);
    const float* g1 = xb + (ok1 ? (gh1 * W_ + gw1) : 0);

    float xr0[16], xr1[16];

    #define LOAD16(dst, gp, okf, qq) do {                                   \
        const float* _p = (gp) + (size_t)(qq) * 16 * (H_ * W_);             \
        _Pragma("unroll")                                                   \
        for (int _i = 0; _i < 16; ++_i)                                     \
            dst[_i] = (okf) ? _p[(size_t)_i * (H_ * W_)] : 0.f;             \
    } while (0)

    // pack 16 floats -> 4 swizzled b128 writes (2 hi chunks + 2 lo chunks)
    #define STAGE(pp, regs) do {                                            \
        s16x8 _vh0, _vh1, _vl0, _vl1;                                       \
        _Pragma("unroll")                                                   \
        for (int _i = 0; _i < 8; ++_i) {                                    \
            unsigned short _h, _l;                                          \
            split_bf16(regs[_i], _h, _l);                                   \
            _vh0[_i] = (short)_h; _vl0[_i] = (short)_l;                     \
            split_bf16(regs[8 + _i], _h, _l);                               \
            _vh1[_i] = (short)_h; _vl1[_i] = (short)_l;                     \
        }                                                                   \
        const int _c0 = (pp) * 2, _c1 = (pp) * 2 + 1;                       \
        const int _s0 = _c0 ^ ((_c0 >> 3) & 7);                             \
        const int _s1 = _c1 ^ ((_c1 >> 3) & 7);                             \
        ((s16x8*)in_hi)[_s0] = _vh0; ((s16x8*)in_hi)[_s1] = _vh1;           \
        ((s16x8*)in_lo)[_s0] = _vl0; ((s16x8*)in_lo)[_s1] = _vl1;           \
    } while (0)

    f32x16 acc[2][2];
    #pragma unroll
    for (int mb = 0; mb < 2; ++mb)
        #pragma unroll
        for (int nb = 0; nb < 2; ++nb)
            #pragma unroll
            for (int j = 0; j < 16; ++j) acc[mb][nb][j] = 0.f;

    const unsigned short* wb = wmix + (size_t)b * 4 * 18432 + lane * 8;

    // prologue: global loads for q=0
    LOAD16(xr0, g0, ok0, 0);
    if (has1) LOAD16(xr1, g1, ok1, 0);

    #pragma unroll 1
    for (int q = 0; q < 4; ++q) {
        __syncthreads();                 // previous q's LDS reads done
        STAGE(p0, xr0);
        if (has1) STAGE(p1, xr1);
        __syncthreads();
        if (q < 3) {                     // T14: prefetch next q under MFMA
            LOAD16(xr0, g0, ok0, q + 1);
            if (has1) LOAD16(xr1, g1, ok1, q + 1);
        }
        const unsigned short* wq = wb + q * 18432;

        // A ping-pong prefetch (global, L2-hit, coalesced 16B/lane)
        s16x8 aH[2][2], aL[2][2];
        #pragma unroll
        for (int mb = 0; mb < 2; ++mb) {
            aH[0][mb] = *(const s16x8*)(wq + (0 + mb) * 512);
            aL[0][mb] = *(const s16x8*)(wq + (2 + mb) * 512);
        }
        #pragma unroll
        for (int tap = 0; tap < 9; ++tap) {
            const int cur = tap & 1, nxt = cur ^ 1;
            if (tap < 8) {
                #pragma unroll
                for (int mb = 0; mb < 2; ++mb) {
                    aH[nxt][mb] = *(const s16x8*)(wq + ((tap + 1) * 4 + 0 + mb) * 512);
                    aL[nxt][mb] = *(const s16x8*)(wq + ((tap + 1) * 4 + 2 + mb) * 512);
                }
            }
            const int kh = tap / 3, kw = tap - kh * 3;
            #pragma unroll
            for (int nb = 0; nb < 2; ++nb) {
                const int rin = wv * 2 + nb + kh;
                const int c   = (rin * 34 + n + kw) * 2 + kseg;
                const int cs  = c ^ ((c >> 3) & 7);
                const s16x8 bhi = ((const s16x8*)in_hi)[cs];
                const s16x8 blo = ((const s16x8*)in_lo)[cs];
                #pragma unroll
                for (int mb = 0; mb < 2; ++mb) {
                    acc[mb][nb] = __builtin_amdgcn_mfma_f32_32x32x16_bf16(aH[cur][mb], bhi, acc[mb][nb], 0, 0, 0);
                    acc[mb][nb] = __builtin_amdgcn_mfma_f32_32x32x16_bf16(aL[cur][mb], bhi, acc[mb][nb], 0, 0, 0);
                    acc[mb][nb] = __builtin_amdgcn_mfma_f32_32x32x16_bf16(aH[cur][mb], blo, acc[mb][nb], 0, 0, 0);
                }
            }
        }
    }

    // epilogue: C/D layout: col = lane&31, row = (r&3)+8*(r>>2)+4*kseg
    #pragma unroll
    for (int mb = 0; mb < 2; ++mb) {
        #pragma unroll
        for (int nb = 0; nb < 2; ++nb) {
            const int hrow = h0 + wv * 2 + nb;
            #pragma unroll
            for (int r = 0; r < 16; ++r) {
                const int oc = mb * 32 + (r & 3) + 8 * (r >> 2) + 4 * kseg;
                y[(((size_t)b * COUT + oc) * H_ + hrow) * W_ + w0 + n] = acc[mb][nb][r];
            }
        }
    }
}

// ---------------------------------------------------------------------------
extern "C" void kernel_launch(void* const* d_in, const int* in_sizes, int n_in,
                              void* d_out, int out_size, void* d_ws, size_t ws_size,
                              hipStream_t stream) {
    const float* x      = (const float*)d_in[0];  // [16,64,256,256]
    const float* weight = (const float*)d_in[1];  // [4,64,64,3,3]
    const float* fc_w   = (const float*)d_in[2];  // [4,64]
    const float* fc_b   = (const float*)d_in[3];  // [4]
    float* out = (float*)d_out;

    float* ws      = (float*)d_ws;
    float* pooled  = ws;                                   // 1024 floats
    float* routing = ws + 1024;                            // 64 floats
    unsigned short* mixed = (unsigned short*)(ws + 1088);  // 1179648 shorts (~2.36 MB)

    pool_kernel<<<B_ * CIN, 256, 0, stream>>>(x, pooled);
    routing_kernel<<<1, 64, 0, stream>>>(pooled, fc_w, fc_b, routing);
    mix_kernel<<<(B_ * 4 * COUT * 16) / 256, 256, 0, stream>>>(routing, weight, mixed);

    dim3 grid(W_ / 32, H_ / 8, B_);
    conv_kernel<<<grid, 256, 0, stream>>>(x, mixed, out);
}

// Round 4
// 640.220 us; speedup vs baseline: 2.3642x; 1.0074x over previous
//
#include <hip/hip_runtime.h>
#include <math.h>

#define B_   16
#define CIN  64
#define COUT 64
#define H_   256
#define W_   256

typedef short s16x8  __attribute__((ext_vector_type(8)));
typedef float f32x16 __attribute__((ext_vector_type(16)));

// Split fp32 into two bf16 (truncation): v = hi + lo + O(2^-16 * v)
__device__ __forceinline__ void split_bf16(float v, unsigned short& hi, unsigned short& lo) {
    unsigned u = __float_as_uint(v);
    hi = (unsigned short)(u >> 16);
    float hif = __uint_as_float(u & 0xffff0000u);
    lo = (unsigned short)(__float_as_uint(v - hif) >> 16);
}

// ---------------------------------------------------------------------------
// 1) pooled[b*64+c] = mean over H*W of inputs[b][c][:][:]
__global__ __launch_bounds__(256) void pool_kernel(const float* __restrict__ x,
                                                   float* __restrict__ pooled) {
    const int plane = blockIdx.x;  // 0..1023 = b*64+c
    const float4* p = (const float4*)(x + (size_t)plane * (H_ * W_));
    float s = 0.f;
    for (int i = threadIdx.x; i < (H_ * W_) / 4; i += 256) {
        float4 v = p[i];
        s += (v.x + v.y) + (v.z + v.w);
    }
    #pragma unroll
    for (int off = 32; off > 0; off >>= 1) s += __shfl_down(s, off);
    __shared__ float red[4];
    if ((threadIdx.x & 63) == 0) red[threadIdx.x >> 6] = s;
    __syncthreads();
    if (threadIdx.x == 0)
        pooled[plane] = (red[0] + red[1] + red[2] + red[3]) * (1.f / (H_ * W_));
}

// ---------------------------------------------------------------------------
// 2) routing[b*4+e] = sigmoid(dot(pooled[b], fc_w[e]) + fc_b[e])
__global__ void routing_kernel(const float* __restrict__ pooled,
                               const float* __restrict__ fc_w,
                               const float* __restrict__ fc_b,
                               float* __restrict__ routing) {
    const int tid = threadIdx.x;          // 64 threads
    const int b = tid >> 2, e = tid & 3;
    float s = fc_b[e];
    for (int c = 0; c < CIN; ++c) s += pooled[b * CIN + c] * fc_w[e * CIN + c];
    routing[b * 4 + e] = 1.f / (1.f + expf(-s));
}

// ---------------------------------------------------------------------------
// 3) mixed weights in exact MFMA A-fragment order, bf16 hi/lo.
// Per (b, q-chunk): 36 fragments of 512 shorts:
//   frag f = tap*4 + half*2 + mb  (tap 0..8, half 0=hi 1=lo, mb 0..1)
//   frag layout: [lane(64)][8]: lane l -> oc = mb*32 + (l&31),
//                               ic = q*16 + (l>>5)*8 + j
__global__ __launch_bounds__(256) void mix_kernel(const float* __restrict__ routing,
                                                  const float* __restrict__ weight,
                                                  unsigned short* __restrict__ mixed) {
    const int gid = blockIdx.x * 256 + threadIdx.x;   // 0..65535
    const int icL = gid & 15;
    const int oc  = (gid >> 4) & 63;
    const int q   = (gid >> 10) & 3;
    const int b   = gid >> 12;
    const int ic  = q * 16 + icL;

    float r[4];
    #pragma unroll
    for (int e = 0; e < 4; ++e) r[e] = routing[b * 4 + e];

    float s[9];
    #pragma unroll
    for (int t = 0; t < 9; ++t) s[t] = 0.f;
    #pragma unroll
    for (int e = 0; e < 4; ++e) {
        const float* wp = weight + (((size_t)e * COUT + oc) * CIN + ic) * 9;
        #pragma unroll
        for (int t = 0; t < 9; ++t) s[t] = fmaf(r[e], wp[t], s[t]);
    }
    unsigned short* base = mixed + (size_t)(b * 4 + q) * 18432;
    const int mb = oc >> 5;
    const int l  = (oc & 31) + ((icL >> 3) << 5);
    const int j  = icL & 7;
    #pragma unroll
    for (int t = 0; t < 9; ++t) {
        unsigned short hi, lo;
        split_bf16(s[t], hi, lo);
        base[(t * 4 + 0 + mb) * 512 + l * 8 + j] = hi;   // half 0
        base[(t * 4 + 2 + mb) * 512 + l * 8 + j] = lo;   // half 1
    }
}

// ---------------------------------------------------------------------------
// 4) conv: tap-decomposed implicit GEMM, split-bf16 3-pass.
// B (input) in LDS, plane-major conflict-free layout:
//   chunk(plane, pos) = plane*340 + pos, plane = hl*2 + ks, pos = r*34 + c.
//   A B-read's 32 lanes (n=0..31) hit 32 consecutive 16B chunks -> no bank
//   conflicts; stage writes are also consecutive-chunk.
// kw-outer MFMA loop: cache 4 B rows x {hi,lo} in regs (dedupe 36->24 reads/q),
// batch 12 A global loads (L2-resident fragment order) per kw ahead of a
// 36-MFMA burst (288cy issue covers ~200cy L2 latency).
// Block: 64oc x 8rows x 32cols, 4 waves (wave wv: rows 2wv, 2wv+1).
// Grid: 4096 1D with bijective XCD-chunked swizzle (4096%8==0).
__global__ __launch_bounds__(256, 2) void conv_kernel(const float* __restrict__ x,
                                                      const unsigned short* __restrict__ wmix,
                                                      float* __restrict__ y) {
    __shared__ __align__(16) unsigned short in_s[4 * 340 * 8];   // 21760 B

    const int tid  = threadIdx.x;
    const int lane = tid & 63;
    const int wv   = tid >> 6;
    const int n    = lane & 31;       // MFMA col / output w-in-tile
    const int kseg = lane >> 5;       // k-half select

    // XCD-chunked bijective swizzle: consecutive logical tiles on one XCD
    const int bid = blockIdx.x;                 // 0..4095
    const int wg  = (bid & 7) * 512 + (bid >> 3);
    const int w0 = (wg & 7) * 32;
    const int h0 = ((wg >> 3) & 31) * 8;
    const int b  = wg >> 8;

    // staging: 340 halo positions; thread covers p0 (+p1 if tid<84)
    const int p0 = tid;
    const int r0 = p0 / 34, c0 = p0 - r0 * 34;
    const int p1 = tid + 256;
    const int r1 = p1 / 34, c1 = p1 - r1 * 34;
    const bool has1 = (p1 < 340);

    const int gh0 = h0 - 1 + r0, gw0 = w0 - 1 + c0;
    const int gh1 = h0 - 1 + r1, gw1 = w0 - 1 + c1;
    const bool ok0 = ((unsigned)gh0 < H_) && ((unsigned)gw0 < W_);
    const bool ok1 = has1 && ((unsigned)gh1 < H_) && ((unsigned)gw1 < W_);

    const float* xb = x + (size_t)b * CIN * H_ * W_;
    const float* g0 = xb + (ok0 ? (gh0 * W_ + gw0) : 0);
    const float* g1 = xb + (ok1 ? (gh1 * W_ + gw1) : 0);

    #define LOAD16(dst, gp, okf, qq) do {                                   \
        const float* _p = (gp) + (size_t)(qq) * 16 * (H_ * W_);             \
        _Pragma("unroll")                                                   \
        for (int _i = 0; _i < 16; ++_i)                                     \
            dst[_i] = (okf) ? _p[(size_t)_i * (H_ * W_)] : 0.f;             \
    } while (0)

    // pack 16 floats -> 4 plane-major chunk writes (hi ks0, hi ks1, lo ks0, lo ks1)
    #define STAGE(pp, regs) do {                                            \
        s16x8 _h0, _h1, _l0, _l1;                                           \
        _Pragma("unroll")                                                   \
        for (int _i = 0; _i < 8; ++_i) {                                    \
            unsigned short _h, _l;                                          \
            split_bf16(regs[_i], _h, _l);                                   \
            _h0[_i] = (short)_h; _l0[_i] = (short)_l;                       \
            split_bf16(regs[8 + _i], _h, _l);                               \
            _h1[_i] = (short)_h; _l1[_i] = (short)_l;                       \
        }                                                                   \
        ((s16x8*)in_s)[0 * 340 + (pp)] = _h0;                               \
        ((s16x8*)in_s)[1 * 340 + (pp)] = _h1;                               \
        ((s16x8*)in_s)[2 * 340 + (pp)] = _l0;                               \
        ((s16x8*)in_s)[3 * 340 + (pp)] = _l1;                               \
    } while (0)

    f32x16 acc[2][2];
    #pragma unroll
    for (int mb = 0; mb < 2; ++mb)
        #pragma unroll
        for (int nb = 0; nb < 2; ++nb)
            #pragma unroll
            for (int j = 0; j < 16; ++j) acc[mb][nb][j] = 0.f;

    const unsigned short* wb = wmix + (size_t)b * 4 * 18432 + lane * 8;

    #pragma unroll 1
    for (int q = 0; q < 4; ++q) {
        __syncthreads();                 // previous q's LDS reads done
        {
            float xr[16];
            LOAD16(xr, g0, ok0, q);
            STAGE(p0, xr);
            if (has1) { LOAD16(xr, g1, ok1, q); STAGE(p1, xr); }
        }
        __syncthreads();
        const unsigned short* wq = wb + q * 18432;

        #pragma unroll
        for (int kw = 0; kw < 3; ++kw) {
            // A fragments for the 3 taps of this kw (global, L2-hit, coalesced)
            s16x8 aH[3][2], aL[3][2];
            #pragma unroll
            for (int kh = 0; kh < 3; ++kh) {
                const int tap = kh * 3 + kw;
                #pragma unroll
                for (int mb = 0; mb < 2; ++mb) {
                    aH[kh][mb] = *(const s16x8*)(wq + (tap * 4 + 0 + mb) * 512);
                    aL[kh][mb] = *(const s16x8*)(wq + (tap * 4 + 2 + mb) * 512);
                }
            }
            // B row-cache: 4 rows x {hi,lo}, conflict-free consecutive-chunk reads
            s16x8 bh[4], bl[4];
            #pragma unroll
            for (int r = 0; r < 4; ++r) {
                const int pos = (wv * 2 + r) * 34 + n + kw;
                bh[r] = ((const s16x8*)in_s)[(0 + kseg) * 340 + pos];
                bl[r] = ((const s16x8*)in_s)[(2 + kseg) * 340 + pos];
            }
            // 36 MFMAs for this kw
            #pragma unroll
            for (int kh = 0; kh < 3; ++kh) {
                #pragma unroll
                for (int nb = 0; nb < 2; ++nb) {
                    const int r = nb + kh;
                    #pragma unroll
                    for (int mb = 0; mb < 2; ++mb) {
                        acc[mb][nb] = __builtin_amdgcn_mfma_f32_32x32x16_bf16(aH[kh][mb], bh[r], acc[mb][nb], 0, 0, 0);
                        acc[mb][nb] = __builtin_amdgcn_mfma_f32_32x32x16_bf16(aL[kh][mb], bh[r], acc[mb][nb], 0, 0, 0);
                        acc[mb][nb] = __builtin_amdgcn_mfma_f32_32x32x16_bf16(aH[kh][mb], bl[r], acc[mb][nb], 0, 0, 0);
                    }
                }
            }
        }
    }

    // epilogue: C/D layout: col = lane&31, row = (r&3)+8*(r>>2)+4*kseg
    #pragma unroll
    for (int mb = 0; mb < 2; ++mb) {
        #pragma unroll
        for (int nb = 0; nb < 2; ++nb) {
            const int hrow = h0 + wv * 2 + nb;
            #pragma unroll
            for (int r = 0; r < 16; ++r) {
                const int oc = mb * 32 + (r & 3) + 8 * (r >> 2) + 4 * kseg;
                y[(((size_t)b * COUT + oc) * H_ + hrow) * W_ + w0 + n] = acc[mb][nb][r];
            }
        }
    }
}

// ---------------------------------------------------------------------------
extern "C" void kernel_launch(void* const* d_in, const int* in_sizes, int n_in,
                              void* d_out, int out_size, void* d_ws, size_t ws_size,
                              hipStream_t stream) {
    const float* x      = (const float*)d_in[0];  // [16,64,256,256]
    const float* weight = (const float*)d_in[1];  // [4,64,64,3,3]
    const float* fc_w   = (const float*)d_in[2];  // [4,64]
    const float* fc_b   = (const float*)d_in[3];  // [4]
    float* out = (float*)d_out;

    float* ws      = (float*)d_ws;
    float* pooled  = ws;                                   // 1024 floats
    float* routing = ws + 1024;                            // 64 floats
    unsigned short* mixed = (unsigned short*)(ws + 1088);  // 1179648 shorts (~2.36 MB)

    pool_kernel<<<B_ * CIN, 256, 0, stream>>>(x, pooled);
    routing_kernel<<<1, 64, 0, stream>>>(pooled, fc_w, fc_b, routing);
    mix_kernel<<<(B_ * 4 * COUT * 16) / 256, 256, 0, stream>>>(routing, weight, mixed);

    conv_kernel<<<4096, 256, 0, stream>>>(x, mixed, out);
}